// Round 10
// baseline (423.274 us; speedup 1.0000x reference)
//
#include <hip/hip_runtime.h>
#include <cstddef>
#include <cstdint>

#define N_NODES 50000
#define D_NODES 20000
#define M_NODES 30000
#define E_EDGES 800000
#define PAIRS_N 100000

typedef unsigned short u16;
typedef unsigned int u32;
typedef short bf16x8 __attribute__((ext_vector_type(8)));
typedef float f32x4 __attribute__((ext_vector_type(4)));

__device__ __forceinline__ float bf2f(u16 u) {
  u32 v = ((u32)u) << 16;
  return __builtin_bit_cast(float, v);
}
__device__ __forceinline__ u16 f2bf(float f) {
  u32 u = __builtin_bit_cast(u32, f);
  u32 r = (u + 0x7fffu + ((u >> 16) & 1u)) >> 16;  // RNE
  return (u16)r;
}
__device__ __forceinline__ u32 pk2(float x, float y) {
  return (u32)f2bf(x) | ((u32)f2bf(y) << 16);
}

// ---------------- weight prep: convert/split all predictor weights -------------
__global__ void wprep_kernel(const float* dfc, const float* mfc,
                             const float* dfc1, const float* mfc1, const float* p0w,
                             u16* wdfc, u16* wmfc, u16* wdfc1s, u16* wmfc1s,
                             u16* wdfc1f, u16* wmfc1f, u16* wp0) {
  int i = blockIdx.x * 256 + threadIdx.x;  // quad index
  const float* s; u16* d;
  if (i < 16384) {
    s = dfc + (size_t)i * 4; d = wdfc + (size_t)i * 4;
  } else if (i < 32768) {
    int l = i - 16384;
    s = mfc + (size_t)l * 4; d = wmfc + (size_t)l * 4;
  } else if (i < 49152) {
    int l = i - 32768, o = l >> 7, kq = l & 127;
    s = dfc1 + (size_t)o * 640 + 128 + kq * 4;
    d = wdfc1s + (size_t)o * 512 + kq * 4;
  } else if (i < 65536) {
    int l = i - 49152, o = l >> 7, kq = l & 127;
    s = mfc1 + (size_t)o * 640 + 128 + kq * 4;
    d = wmfc1s + (size_t)o * 512 + kq * 4;
  } else if (i < 69632) {
    int l = i - 65536, o = l >> 5, kq = l & 31;
    s = dfc1 + (size_t)o * 640 + kq * 4;
    d = wdfc1f + (size_t)o * 128 + kq * 4;
  } else if (i < 73728) {
    int l = i - 69632, o = l >> 5, kq = l & 31;
    s = mfc1 + (size_t)o * 640 + kq * 4;
    d = wmfc1f + (size_t)o * 128 + kq * 4;
  } else if (i < 81920) {
    int l = i - 73728;
    s = p0w + (size_t)l * 4; d = wp0 + (size_t)l * 4;
  } else return;
  float4 v = *(const float4*)s;
  ushort4 o4;
  o4.x = f2bf(v.x); o4.y = f2bf(v.y); o4.z = f2bf(v.z); o4.w = f2bf(v.w);
  *(ushort4*)d = o4;
}

// ---------------- weight combine: G_k = sum_{p+j=k} fc_p * W'_pj * W_j ----------
__global__ void wcomb1_kernel(const float* __restrict__ l1w, const float* __restrict__ l0w,
                              float* __restrict__ Tmp) {
  int pj = blockIdx.x;          // 0..8
  int p = pj / 3, j = pj % 3;
  int o = blockIdx.y;           // 0..127
  int i = threadIdx.x;          // 0..127
  const float* wp = l1w + (size_t)p * 49152 + (size_t)o * 384 + 128 * j;
  const float* wj = l0w + (size_t)j * 16384 + i;
  float acc = 0.f;
#pragma unroll 4
  for (int t = 0; t < 128; ++t) acc += wp[t] * wj[(size_t)t * 128];
  Tmp[(size_t)pj * 16384 + (size_t)o * 128 + i] = acc;
}
__global__ void wcomb2_kernel(const float* __restrict__ fcw, const float* __restrict__ Tmp,
                              u16* __restrict__ G) {
  int k = blockIdx.x;           // 0..4
  int of = blockIdx.y;          // 0..127
  int i = threadIdx.x;          // 0..127
  float acc = 0.f;
  int plo = (k > 2) ? (k - 2) : 0;
  int phi = (k < 2) ? k : 2;
  for (int p = plo; p <= phi; ++p) {
    int j = k - p;
    const float* fp = fcw + (size_t)of * 384 + 128 * p;
    const float* tp = Tmp + (size_t)(p * 3 + j) * 16384 + i;
#pragma unroll 4
    for (int t = 0; t < 128; ++t) acc += fp[t] * tp[(size_t)t * 128];
  }
  G[(size_t)of * 640 + 128 * k + i] = f2bf(acc);
}

// ---------------- CSR build ----------------
__global__ void zero_int_kernel(int* p, int n) {
  int i = blockIdx.x * 256 + threadIdx.x;
  if (i < n) p[i] = 0;
}
__global__ void deg_count_kernel(const int* __restrict__ dst, int* __restrict__ degs, int e) {
  int i = blockIdx.x * 256 + threadIdx.x;
  if (i < e) atomicAdd(&degs[dst[i]], 1);
}
__global__ void norm_reduce_kernel(const int* __restrict__ degs, float* __restrict__ norm,
                                   int n, int* __restrict__ bsums) {
  __shared__ int s[256];
  int t = threadIdx.x;
  int i = blockIdx.x * 256 + t;
  int d = (i < n) ? degs[i] : 0;
  if (i < n) norm[i] = rsqrtf(fmaxf((float)d, 1.0f));
  s[t] = d;
  __syncthreads();
  for (int st = 128; st > 0; st >>= 1) {
    if (t < st) s[t] += s[t + st];
    __syncthreads();
  }
  if (t == 0) bsums[blockIdx.x] = s[0];
}
__global__ void scan_small_kernel(int* b, int nb) {
  __shared__ int s[256];
  int t = threadIdx.x;
  int orig = (t < nb) ? b[t] : 0;
  s[t] = orig;
  __syncthreads();
  for (int st = 1; st < 256; st <<= 1) {
    int v = (t >= st) ? s[t - st] : 0;
    __syncthreads();
    s[t] += v;
    __syncthreads();
  }
  if (t < nb) b[t] = s[t] - orig;
}
__global__ void scan_final_kernel(const int* __restrict__ degs, const int* __restrict__ boff,
                                  int* __restrict__ out, int* __restrict__ cursor,
                                  int n, int total) {
  __shared__ int s[256];
  int t = threadIdx.x;
  int i = blockIdx.x * 256 + t;
  int orig = (i < n) ? degs[i] : 0;
  s[t] = orig;
  __syncthreads();
  for (int st = 1; st < 256; st <<= 1) {
    int v = (t >= st) ? s[t - st] : 0;
    __syncthreads();
    s[t] += v;
    __syncthreads();
  }
  if (i < n) {
    int v = boff[blockIdx.x] + s[t] - orig;
    out[i] = v;
    cursor[i] = v;
  }
  if (i == 0) out[n] = total;
}
__global__ void fill_csr_kernel(const int* __restrict__ esrc, const int* __restrict__ edst,
                                int* __restrict__ cursor, int* __restrict__ csr_src, int e) {
  int i = blockIdx.x * 256 + threadIdx.x;
  if (i < e) {
    int p = atomicAdd(&cursor[edst[i]], 1);
    csr_src[p] = esrc[i];
  }
}

// ---------------- chunked L2-resident propagation ----------------
// 4 channel-chunks of 32 (3.2 MB working set, fits per-XCD L2). Grid = 4*3125
// blocks, chunk = blockIdx/3125 (in-order dispatch => phases mostly sequential).
// Block = 16 nodes (4 waves x 4 groups x 16 lanes); lane = 2 channels (4B load).
// src idx broadcast via __shfl (per-group lane base); 16 unconditional loads in
// flight, predicated accumulate. Input pre-scaled by norm[src].
__global__ void prop_kernel(const u16* __restrict__ in,
                            u16* __restrict__ outu, int ldu, int cOff,
                            u16* __restrict__ outs,
                            const int* __restrict__ off, const int* __restrict__ srcs,
                            const float* __restrict__ norm) {
  const int tid = threadIdx.x;
  const int li = tid & 15;
  const int blk = (int)blockIdx.x;
  const int chunk = blk / 3125;
  const int node = (blk % 3125) * 16 + (tid >> 4);
  const int c0 = chunk * 32;
  const int srcLaneBase = ((tid >> 4) & 3) << 4;   // group-in-wave * 16
  const int e0 = off[node], e1 = off[node + 1];
  float a0 = 0.f, a1 = 0.f;
  const u16* basec = in + c0 + (li << 1);
  for (int eb = e0; eb < e1; eb += 16) {
    int nE = e1 - eb; if (nE > 16) nE = 16;
    int myE = srcs[eb + ((li < nE) ? li : (nE - 1))];
    u32 v[16];
#pragma unroll
    for (int i = 0; i < 16; ++i) {
      int s = __shfl(myE, srcLaneBase + i, 64);
      v[i] = *(const u32*)(basec + ((size_t)s << 7));
    }
#pragma unroll
    for (int i = 0; i < 16; ++i) {
      if (i < nE) { a0 += bf2f((u16)v[i]); a1 += bf2f((u16)(v[i] >> 16)); }
    }
  }
  float nd = norm[node];
  *(u32*)(outu + (size_t)node * ldu + cOff + c0 + (li << 1)) = pk2(a0 * nd, a1 * nd);
  if (outs) {
    float nd2 = nd * nd;
    *(u32*)(outs + ((size_t)node << 7) + c0 + (li << 1)) = pk2(a0 * nd2, a1 * nd2);
  }
}

// ---------------- proj: sims(fp32) GEMM, A-upfront-in-regs, W 2-deep pipelined ---
__global__ __launch_bounds__(256) void proj_kernel(
    const float* __restrict__ dsim, const float* __restrict__ msim,
    const u16* __restrict__ Wdfc, const u16* __restrict__ Wmfc,
    const u16* __restrict__ Wdfc1s, const u16* __restrict__ Wmfc1s,
    const float* __restrict__ dfcb, const float* __restrict__ mfcb,
    int gdseg, int gseg,
    u16* __restrict__ HCAT, u16* __restrict__ HSa, float* __restrict__ SB,
    const float* __restrict__ normp) {
  __shared__ u32 As[32 * 32];     // 4 KB
  __shared__ u32 Ws[128 * 32];    // 16 KB
  const int tid = threadIdx.x;
  int b = (int)blockIdx.x;
  const bool sbseg = b >= gseg;
  if (sbseg) b -= gseg;
  const bool mseg = b >= gdseg;
  const int brow = mseg ? D_NODES + (b - gdseg) * 32 : b * 32;
  const int bound = mseg ? N_NODES : D_NODES;
  const float* A = mseg ? msim : dsim;   // global-row indexed
  const u16* W = sbseg ? (mseg ? Wmfc1s : Wdfc1s) : (mseg ? Wmfc : Wdfc);
  const float* bias = mseg ? mfcb : dfcb;

  const int lane = tid & 63, wv = tid >> 6;
  const int fr = lane & 15, fg = lane >> 4;
  const int sr = tid >> 3, sk = tid & 7;
  const int swc = tid >> 1, sh = tid & 1;
  const int prow = (brow + sr < bound) ? (brow + sr) : (bound - 1);

  // ---- all A upfront: 8 chunks x 8 fp32 -> bf16 regs (one latency exposure)
  const float* ap = A + (size_t)prow * 512 + sk * 8;
  uint4 aq[8];
#pragma unroll
  for (int j = 0; j < 8; ++j) {
    float4 f0 = ((const float4*)(ap + j * 64))[0];
    float4 f1 = ((const float4*)(ap + j * 64))[1];
    aq[j] = make_uint4(pk2(f0.x, f0.y), pk2(f0.z, f0.w), pk2(f1.x, f1.y), pk2(f1.z, f1.w));
  }

  // ---- W pipeline (L2-hot)
  const u16* wrow = W + (size_t)swc * 512 + sh * 32;
  uint4 pw0 = *(const uint4*)(wrow);
  uint4 pw1 = *(const uint4*)(wrow + 8);
  uint4 pw2 = *(const uint4*)(wrow + 16);
  uint4 pw3 = *(const uint4*)(wrow + 24);

  f32x4 acc[2][2];
#pragma unroll
  for (int m = 0; m < 2; ++m)
#pragma unroll
    for (int n = 0; n < 2; ++n) acc[m][n] = (f32x4){0.f, 0.f, 0.f, 0.f};

#pragma unroll
  for (int j = 0; j < 8; ++j) {
    __syncthreads();
    *(uint4*)&As[sr * 32 + (sk ^ (sr & 7)) * 4] = aq[j];
    *(uint4*)&Ws[swc * 32 + ((sh * 4 + 0) ^ (swc & 7)) * 4] = pw0;
    *(uint4*)&Ws[swc * 32 + ((sh * 4 + 1) ^ (swc & 7)) * 4] = pw1;
    *(uint4*)&Ws[swc * 32 + ((sh * 4 + 2) ^ (swc & 7)) * 4] = pw2;
    *(uint4*)&Ws[swc * 32 + ((sh * 4 + 3) ^ (swc & 7)) * 4] = pw3;
    __syncthreads();
    if (j < 7) {
      const u16* wp = wrow + (j + 1) * 64;
      pw0 = *(const uint4*)(wp);
      pw1 = *(const uint4*)(wp + 8);
      pw2 = *(const uint4*)(wp + 16);
      pw3 = *(const uint4*)(wp + 24);
    }
#pragma unroll
    for (int kk2 = 0; kk2 < 2; ++kk2) {
      int gix = kk2 * 4 + fg;
      int r0 = fr, r1 = 16 + fr;
      bf16x8 aF0 = *(const bf16x8*)&As[r0 * 32 + (gix ^ (r0 & 7)) * 4];
      bf16x8 aF1 = *(const bf16x8*)&As[r1 * 32 + (gix ^ (r1 & 7)) * 4];
#pragma unroll
      for (int n = 0; n < 2; ++n) {
        int cr = wv * 32 + n * 16 + fr;
        bf16x8 bF = *(const bf16x8*)&Ws[cr * 32 + (gix ^ (cr & 7)) * 4];
        acc[0][n] = __builtin_amdgcn_mfma_f32_16x16x32_bf16(aF0, bF, acc[0][n], 0, 0, 0);
        acc[1][n] = __builtin_amdgcn_mfma_f32_16x16x32_bf16(aF1, bF, acc[1][n], 0, 0, 0);
      }
    }
  }

  // ---- epilogue: D lane map col=lane&15, row=(lane>>4)*4+i  [m89]
#pragma unroll
  for (int m = 0; m < 2; ++m) {
#pragma unroll
    for (int n = 0; n < 2; ++n) {
      int ccol = wv * 32 + n * 16 + fr;
#pragma unroll
      for (int i = 0; i < 4; ++i) {
        int row = brow + m * 16 + fg * 4 + i;
        if (row < bound) {
          if (sbseg) {
            SB[((size_t)row << 7) + ccol] = acc[m][n][i];
          } else {
            float v = acc[m][n][i] + bias[ccol];
            HCAT[(size_t)row * 640 + ccol] = f2bf(v);
            HSa[((size_t)row << 7) + ccol] = f2bf(v * normp[row]);
          }
        }
      }
    }
  }
}

// ---------------- bf16 MFMA GEMM (BM=32, BN=128, BK=64) -----------
__global__ __launch_bounds__(256) void gemm128_kernel(
    const u16* __restrict__ A1, int lda1, int K1,
    const u16* __restrict__ A2, int lda2, int K2,
    const int* __restrict__ gsrc, const int* __restrict__ gdst,
    const u16* __restrict__ Wa, const u16* __restrict__ Wb,
    const float* __restrict__ biasa, const float* __restrict__ biasb,
    int splitB, int rowD, int boundA, int nrows,
    u16* __restrict__ Cu, int ldcu,
    const float* __restrict__ SBadd,
    const float* __restrict__ p1w, const float* __restrict__ p1b, float* __restrict__ outf,
    int act) {
  __shared__ u32 As[32 * 32];    // 4 KB
  __shared__ u32 Ws[128 * 32];   // 16 KB
  const int tid = threadIdx.x;
  const bool segb = (int)blockIdx.x >= splitB;
  const int brow = segb ? rowD + ((int)blockIdx.x - splitB) * 32 : (int)blockIdx.x * 32;
  const int bound = segb ? nrows : boundA;
  const u16* W = segb ? Wb : Wa;
  const float* bias = segb ? biasb : biasa;
  const int K = K1 + K2;
  const int lane = tid & 63;
  const int wv = tid >> 6;
  const int fr = lane & 15;
  const int fg = lane >> 4;

  f32x4 acc[2][2];
#pragma unroll
  for (int m = 0; m < 2; ++m)
#pragma unroll
    for (int n = 0; n < 2; ++n) acc[m][n] = (f32x4){0.f, 0.f, 0.f, 0.f};

  const int sr = tid >> 3, sk = tid & 7;     // A: row, granule (8 bf16)
  const int swc = tid >> 1, sh = tid & 1;    // W: row, 32-elem half
  const int prow = (brow + sr < bound) ? (brow + sr) : (bound - 1);
  const int rA = gsrc ? gsrc[prow] : prow;
  const int rB = gsrc ? gdst[prow] : prow;

  for (int kc = 0; kc < K; kc += 64) {
    // ---- A: 8 k-elems per thread
    uint4 qa;
    {
      bool seg1 = kc < K1;
      int kk = (seg1 ? kc : kc - K1) + sk * 8;
      const u16* Av = seg1 ? A1 : A2;
      int ld = seg1 ? lda1 : lda2;
      int row = seg1 ? rA : rB;
      qa = *(const uint4*)(Av + (size_t)row * ld + kk);
    }
    // ---- W: 32 k-elems per thread
    const u16* wp = W + (size_t)swc * K + kc + sh * 32;
    uint4 qw0 = *(const uint4*)(wp);
    uint4 qw1 = *(const uint4*)(wp + 8);
    uint4 qw2 = *(const uint4*)(wp + 16);
    uint4 qw3 = *(const uint4*)(wp + 24);

    __syncthreads();
    *(uint4*)&As[sr * 32 + (sk ^ (sr & 7)) * 4] = qa;
    *(uint4*)&Ws[swc * 32 + ((sh * 4 + 0) ^ (swc & 7)) * 4] = qw0;
    *(uint4*)&Ws[swc * 32 + ((sh * 4 + 1) ^ (swc & 7)) * 4] = qw1;
    *(uint4*)&Ws[swc * 32 + ((sh * 4 + 2) ^ (swc & 7)) * 4] = qw2;
    *(uint4*)&Ws[swc * 32 + ((sh * 4 + 3) ^ (swc & 7)) * 4] = qw3;
    __syncthreads();

#pragma unroll
    for (int kk2 = 0; kk2 < 2; ++kk2) {
      int gix = kk2 * 4 + fg;
      int r0 = fr, r1 = 16 + fr;
      bf16x8 aF0 = *(const bf16x8*)&As[r0 * 32 + (gix ^ (r0 & 7)) * 4];
      bf16x8 aF1 = *(const bf16x8*)&As[r1 * 32 + (gix ^ (r1 & 7)) * 4];
#pragma unroll
      for (int n = 0; n < 2; ++n) {
        int cr = wv * 32 + n * 16 + fr;
        bf16x8 bF = *(const bf16x8*)&Ws[cr * 32 + (gix ^ (cr & 7)) * 4];
        acc[0][n] = __builtin_amdgcn_mfma_f32_16x16x32_bf16(aF0, bF, acc[0][n], 0, 0, 0);
        acc[1][n] = __builtin_amdgcn_mfma_f32_16x16x32_bf16(aF1, bF, acc[1][n], 0, 0, 0);
      }
    }
  }

  if (act == 3) {
    float part[2][4];
#pragma unroll
    for (int m = 0; m < 2; ++m)
#pragma unroll
      for (int i = 0; i < 4; ++i) part[m][i] = 0.f;
#pragma unroll
    for (int n = 0; n < 2; ++n) {
      int ccol = wv * 32 + n * 16 + fr;
      float b = bias[ccol];
      float pw = p1w[ccol];
#pragma unroll
      for (int m = 0; m < 2; ++m)
#pragma unroll
        for (int i = 0; i < 4; ++i) {
          float v = fmaxf(acc[m][n][i] + b, 0.f);
          part[m][i] += v * pw;
        }
    }
#pragma unroll
    for (int mask = 1; mask <= 8; mask <<= 1)
#pragma unroll
      for (int m = 0; m < 2; ++m)
#pragma unroll
        for (int i = 0; i < 4; ++i) part[m][i] += __shfl_xor(part[m][i], mask);
    __syncthreads();
    float* sred = (float*)As;        // [4][32]
    if (fr == 0) {
#pragma unroll
      for (int m = 0; m < 2; ++m)
#pragma unroll
        for (int i = 0; i < 4; ++i) sred[wv * 32 + m * 16 + fg * 4 + i] = part[m][i];
    }
    __syncthreads();
    if (tid < 32) {
      int row = brow + tid;
      if (row < bound) {
        float s = sred[tid] + sred[32 + tid] + sred[64 + tid] + sred[96 + tid] + p1b[0];
        outf[row] = 1.f / (1.f + expf(-s));
      }
    }
    return;
  }

  // ---- epilogue: D lane map col=lane&15, row=(lane>>4)*4+i  [m89]
#pragma unroll
  for (int m = 0; m < 2; ++m) {
#pragma unroll
    for (int n = 0; n < 2; ++n) {
      int ccol = wv * 32 + n * 16 + fr;
      float b = bias ? bias[ccol] : 0.f;
#pragma unroll
      for (int i = 0; i < 4; ++i) {
        int row = brow + m * 16 + fg * 4 + i;
        if (row < bound) {
          float v = acc[m][n][i] + b;
          if (SBadd) v += SBadd[((size_t)row << 7) + ccol];
          if (act == 1) v = (v > 0.f) ? v : (expf(v) - 1.f);
          Cu[(size_t)row * ldcu + ccol] = f2bf(v);
        }
      }
    }
  }
}

// ---------------- host launcher ----------------
extern "C" void kernel_launch(void* const* d_in, const int* in_sizes, int n_in,
                              void* d_out, int out_size, void* d_ws, size_t ws_size,
                              hipStream_t stream) {
  const float* d_sim   = (const float*)d_in[0];
  const float* m_sim   = (const float*)d_in[1];
  const int*   e_src   = (const int*)d_in[2];
  const int*   e_dst   = (const int*)d_in[3];
  const int*   p_src   = (const int*)d_in[4];
  const int*   p_dst   = (const int*)d_in[5];
  const float* d_fc_w  = (const float*)d_in[6];
  const float* d_fc_b  = (const float*)d_in[7];
  const float* m_fc_w  = (const float*)d_in[8];
  const float* m_fc_b  = (const float*)d_in[9];
  const float* l0_w    = (const float*)d_in[10];
  const float* l1_w    = (const float*)d_in[11];
  const float* fc_w    = (const float*)d_in[12];
  const float* d_fc1_w = (const float*)d_in[13];
  const float* d_fc1_b = (const float*)d_in[14];
  const float* m_fc1_w = (const float*)d_in[15];
  const float* m_fc1_b = (const float*)d_in[16];
  const float* p0_w    = (const float*)d_in[17];
  const float* p0_b    = (const float*)d_in[18];
  const float* p1_w    = (const float*)d_in[19];
  const float* p1_b    = (const float*)d_in[20];
  float* out = (float*)d_out;

  const int N = N_NODES, D = D_NODES, M = M_NODES, E = E_EDGES, NP = PAIRS_N;

  // ---- workspace layout (u16 units)
  u16* ws16 = (u16*)d_ws;
  u16* HCAT = ws16;                         // [N,640]
  u16* HSa  = HCAT + (size_t)N * 640;       // [N,128]
  u16* HSb  = HSa + (size_t)N * 128;        // [N,128]
  u16* FE   = HSb + (size_t)N * 128;        // [N,128] feats
  u16* HB   = FE  + (size_t)N * 128;        // [N,128] h
  u16* wb_dfc   = HB + (size_t)N * 128;     // 65536
  u16* wb_mfc   = wb_dfc   + 65536;
  u16* wb_dfc1s = wb_mfc   + 65536;         // 65536
  u16* wb_mfc1s = wb_dfc1s + 65536;
  u16* wb_dfc1f = wb_mfc1s + 65536;         // 16384
  u16* wb_mfc1f = wb_dfc1f + 16384;
  u16* wb_p0    = wb_mfc1f + 16384;         // 32768
  u16* wb_G     = wb_p0    + 32768;         // 81920 ([128][640])
  u16* wend     = wb_G     + 81920;
  size_t off16 = (size_t)(wend - ws16);
  off16 = (off16 + 1) & ~(size_t)1;
  float* SB    = (float*)(ws16 + off16);    // [N,128] f32
  float* Tmp   = SB + (size_t)N * 128;      // 9*128*128 f32
  float* normp = Tmp + 9 * 16384;
  int* degs    = (int*)(normp + N);
  int* csr_off = degs + N;                  // N+1
  int* cursor  = csr_off + N + 1;           // N
  int* csr_src = cursor + N;                // E
  int* bsums   = csr_src + E;               // <=256

  const int nb = (N + 255) / 256;
  const int eb = (E + 255) / 256;

  // ---- weight prep + combine (independent of graph)
  wprep_kernel<<<320, 256, 0, stream>>>(d_fc_w, m_fc_w, d_fc1_w, m_fc1_w, p0_w,
                                        wb_dfc, wb_mfc, wb_dfc1s, wb_mfc1s,
                                        wb_dfc1f, wb_mfc1f, wb_p0);
  wcomb1_kernel<<<dim3(9, 128), 128, 0, stream>>>(l1_w, l0_w, Tmp);
  wcomb2_kernel<<<dim3(5, 128), 128, 0, stream>>>(fc_w, Tmp, wb_G);

  // ---- degrees, norm, CSR-by-dst
  zero_int_kernel<<<nb, 256, 0, stream>>>(degs, N);
  deg_count_kernel<<<eb, 256, 0, stream>>>(e_dst, degs, E);
  norm_reduce_kernel<<<nb, 256, 0, stream>>>(degs, normp, N, bsums);
  scan_small_kernel<<<1, 256, 0, stream>>>(bsums, nb);
  scan_final_kernel<<<nb, 256, 0, stream>>>(degs, bsums, csr_off, cursor, N, E);
  fill_csr_kernel<<<eb, 256, 0, stream>>>(e_src, e_dst, cursor, csr_src, E);

  const int GDseg = D / 32;                  // 625
  const int GMseg = (M + 31) / 32;           // 938
  const int GSEG = GDseg + GMseg;            // 1563
  const int GN = (N + 31) / 32;              // 1563
  const int GP = (NP + 31) / 32;             // 3125
  const int GPROP = 4 * 3125;                // 4 chunks x 3125 blocks

  // ---- proj (grid 2x: H0 + SB partial, one sims read window)
  proj_kernel<<<2 * GSEG, 256, 0, stream>>>(
      d_sim, m_sim, wb_dfc, wb_mfc, wb_dfc1s, wb_mfc1s, d_fc_b, m_fc_b,
      GDseg, GSEG, HCAT, HSa, SB, normp);

  // ---- 4 sequential chunked props: H1..H4 -> HCAT col-blocks, scaled ping-pong
  prop_kernel<<<GPROP, 256, 0, stream>>>(HSa, HCAT, 640, 128, HSb, csr_off, csr_src, normp);
  prop_kernel<<<GPROP, 256, 0, stream>>>(HSb, HCAT, 640, 256, HSa, csr_off, csr_src, normp);
  prop_kernel<<<GPROP, 256, 0, stream>>>(HSa, HCAT, 640, 384, HSb, csr_off, csr_src, normp);
  prop_kernel<<<GPROP, 256, 0, stream>>>(HSb, HCAT, 640, 512, nullptr, csr_off, csr_src, normp);

  // ---- collapsed mixhop+fc: feats = HCAT [N,640] @ G^T -> FE
  gemm128_kernel<<<GN, 256, 0, stream>>>(
      HCAT, 640, 640, HCAT, 640, 0, nullptr, nullptr,
      wb_G, wb_G, nullptr, nullptr, GN, 0, N, N,
      FE, 128, nullptr, nullptr, nullptr, nullptr, 0);

  // ---- fc1-lite (+SB +bias, ELU): h -> HB
  gemm128_kernel<<<GSEG, 256, 0, stream>>>(
      FE, 128, 128, FE, 128, 0, nullptr, nullptr,
      wb_dfc1f, wb_mfc1f, d_fc1_b, m_fc1_b, GDseg, D, D, N,
      HB, 128, SB, nullptr, nullptr, nullptr, 1);

  // ---- predictor p0 (gathered concat) + ReLU + dot(p1) + sigmoid -> out
  gemm128_kernel<<<GP, 256, 0, stream>>>(
      HB, 128, 128, HB, 128, 128, p_src, p_dst,
      wb_p0, wb_p0, p0_b, p0_b, GP, 0, NP, NP,
      nullptr, 128, nullptr, p1_w, p1_b, out, 3);

  (void)in_sizes; (void)n_in; (void)out_size; (void)ws_size;
}

// Round 11
// 413.367 us; speedup vs baseline: 1.0240x; 1.0240x over previous
//
#include <hip/hip_runtime.h>
#include <cstddef>
#include <cstdint>

#define N_NODES 50000
#define D_NODES 20000
#define M_NODES 30000
#define E_EDGES 800000
#define PAIRS_N 100000

typedef unsigned short u16;
typedef unsigned int u32;
typedef short bf16x8 __attribute__((ext_vector_type(8)));
typedef float f32x4 __attribute__((ext_vector_type(4)));

__device__ __forceinline__ float bf2f(u16 u) {
  u32 v = ((u32)u) << 16;
  return __builtin_bit_cast(float, v);
}
__device__ __forceinline__ u16 f2bf(float f) {
  u32 u = __builtin_bit_cast(u32, f);
  u32 r = (u + 0x7fffu + ((u >> 16) & 1u)) >> 16;  // RNE
  return (u16)r;
}
__device__ __forceinline__ u32 pk2(float x, float y) {
  return (u32)f2bf(x) | ((u32)f2bf(y) << 16);
}

// ---- shared MFMA sub-block: 2x2 frags on a 32x(64k) A-buf and 128x(64k) W-buf ----
__device__ __forceinline__ void mfma_block(const u32* __restrict__ Asb,
                                           const u32* __restrict__ Wsb,
                                           int fr, int fg, int wv, f32x4 acc[2][2]) {
#pragma unroll
  for (int kk2 = 0; kk2 < 2; ++kk2) {
    int gix = kk2 * 4 + fg;
    int r0 = fr, r1 = 16 + fr;
    bf16x8 aF0 = *(const bf16x8*)&Asb[r0 * 32 + (gix ^ (r0 & 7)) * 4];
    bf16x8 aF1 = *(const bf16x8*)&Asb[r1 * 32 + (gix ^ (r1 & 7)) * 4];
#pragma unroll
    for (int n = 0; n < 2; ++n) {
      int cr = wv * 32 + n * 16 + fr;
      bf16x8 bF = *(const bf16x8*)&Wsb[cr * 32 + (gix ^ (cr & 7)) * 4];
      acc[0][n] = __builtin_amdgcn_mfma_f32_16x16x32_bf16(aF0, bF, acc[0][n], 0, 0, 0);
      acc[1][n] = __builtin_amdgcn_mfma_f32_16x16x32_bf16(aF1, bF, acc[1][n], 0, 0, 0);
    }
  }
}

// ---------------- weight prep: convert/split all predictor weights -------------
__global__ void wprep_kernel(const float* dfc, const float* mfc,
                             const float* dfc1, const float* mfc1, const float* p0w,
                             u16* wdfc, u16* wmfc, u16* wdfc1s, u16* wmfc1s,
                             u16* wdfc1f, u16* wmfc1f, u16* wp0) {
  int i = blockIdx.x * 256 + threadIdx.x;  // quad index
  const float* s; u16* d;
  if (i < 16384) {
    s = dfc + (size_t)i * 4; d = wdfc + (size_t)i * 4;
  } else if (i < 32768) {
    int l = i - 16384;
    s = mfc + (size_t)l * 4; d = wmfc + (size_t)l * 4;
  } else if (i < 49152) {
    int l = i - 32768, o = l >> 7, kq = l & 127;
    s = dfc1 + (size_t)o * 640 + 128 + kq * 4;
    d = wdfc1s + (size_t)o * 512 + kq * 4;
  } else if (i < 65536) {
    int l = i - 49152, o = l >> 7, kq = l & 127;
    s = mfc1 + (size_t)o * 640 + 128 + kq * 4;
    d = wmfc1s + (size_t)o * 512 + kq * 4;
  } else if (i < 69632) {
    int l = i - 65536, o = l >> 5, kq = l & 31;
    s = dfc1 + (size_t)o * 640 + kq * 4;
    d = wdfc1f + (size_t)o * 128 + kq * 4;
  } else if (i < 73728) {
    int l = i - 69632, o = l >> 5, kq = l & 31;
    s = mfc1 + (size_t)o * 640 + kq * 4;
    d = wmfc1f + (size_t)o * 128 + kq * 4;
  } else if (i < 81920) {
    int l = i - 73728;
    s = p0w + (size_t)l * 4; d = wp0 + (size_t)l * 4;
  } else return;
  float4 v = *(const float4*)s;
  ushort4 o4;
  o4.x = f2bf(v.x); o4.y = f2bf(v.y); o4.z = f2bf(v.z); o4.w = f2bf(v.w);
  *(ushort4*)d = o4;
}

// ---------------- weight combine: G_k = sum_{p+j=k} fc_p * W'_pj * W_j ----------
__global__ void wcomb1_kernel(const float* __restrict__ l1w, const float* __restrict__ l0w,
                              float* __restrict__ Tmp) {
  int pj = blockIdx.x;          // 0..8
  int p = pj / 3, j = pj % 3;
  int o = blockIdx.y;           // 0..127
  int i = threadIdx.x;          // 0..127
  const float* wp = l1w + (size_t)p * 49152 + (size_t)o * 384 + 128 * j;
  const float* wj = l0w + (size_t)j * 16384 + i;
  float acc = 0.f;
#pragma unroll 4
  for (int t = 0; t < 128; ++t) acc += wp[t] * wj[(size_t)t * 128];
  Tmp[(size_t)pj * 16384 + (size_t)o * 128 + i] = acc;
}
__global__ void wcomb2_kernel(const float* __restrict__ fcw, const float* __restrict__ Tmp,
                              u16* __restrict__ G) {
  int k = blockIdx.x;           // 0..4
  int of = blockIdx.y;          // 0..127
  int i = threadIdx.x;          // 0..127
  float acc = 0.f;
  int plo = (k > 2) ? (k - 2) : 0;
  int phi = (k < 2) ? k : 2;
  for (int p = plo; p <= phi; ++p) {
    int j = k - p;
    const float* fp = fcw + (size_t)of * 384 + 128 * p;
    const float* tp = Tmp + (size_t)(p * 3 + j) * 16384 + i;
#pragma unroll 4
    for (int t = 0; t < 128; ++t) acc += fp[t] * tp[(size_t)t * 128];
  }
  G[(size_t)of * 640 + 128 * k + i] = f2bf(acc);
}

// ---------------- CSR build ----------------
__global__ void zero_int_kernel(int* p, int n) {
  int i = blockIdx.x * 256 + threadIdx.x;
  if (i < n) p[i] = 0;
}
__global__ void deg_count_kernel(const int* __restrict__ dst, int* __restrict__ degs, int e) {
  int i = blockIdx.x * 256 + threadIdx.x;
  if (i < e) atomicAdd(&degs[dst[i]], 1);
}
__global__ void norm_reduce_kernel(const int* __restrict__ degs, float* __restrict__ norm,
                                   int n, int* __restrict__ bsums) {
  __shared__ int s[256];
  int t = threadIdx.x;
  int i = blockIdx.x * 256 + t;
  int d = (i < n) ? degs[i] : 0;
  if (i < n) norm[i] = rsqrtf(fmaxf((float)d, 1.0f));
  s[t] = d;
  __syncthreads();
  for (int st = 128; st > 0; st >>= 1) {
    if (t < st) s[t] += s[t + st];
    __syncthreads();
  }
  if (t == 0) bsums[blockIdx.x] = s[0];
}
__global__ void scan_small_kernel(int* b, int nb) {
  __shared__ int s[256];
  int t = threadIdx.x;
  int orig = (t < nb) ? b[t] : 0;
  s[t] = orig;
  __syncthreads();
  for (int st = 1; st < 256; st <<= 1) {
    int v = (t >= st) ? s[t - st] : 0;
    __syncthreads();
    s[t] += v;
    __syncthreads();
  }
  if (t < nb) b[t] = s[t] - orig;
}
__global__ void scan_final_kernel(const int* __restrict__ degs, const int* __restrict__ boff,
                                  int* __restrict__ out, int* __restrict__ cursor,
                                  int n, int total) {
  __shared__ int s[256];
  int t = threadIdx.x;
  int i = blockIdx.x * 256 + t;
  int orig = (i < n) ? degs[i] : 0;
  s[t] = orig;
  __syncthreads();
  for (int st = 1; st < 256; st <<= 1) {
    int v = (t >= st) ? s[t - st] : 0;
    __syncthreads();
    s[t] += v;
    __syncthreads();
  }
  if (i < n) {
    int v = boff[blockIdx.x] + s[t] - orig;
    out[i] = v;
    cursor[i] = v;
  }
  if (i == 0) out[n] = total;
}
__global__ void fill_csr_kernel(const int* __restrict__ esrc, const int* __restrict__ edst,
                                int* __restrict__ cursor, int* __restrict__ csr_src, int e) {
  int i = blockIdx.x * 256 + threadIdx.x;
  if (i < e) {
    int p = atomicAdd(&cursor[edst[i]], 1);
    csr_src[p] = esrc[i];
  }
}

// ---------------- wave-per-node 128-wide propagation on pre-scaled input --------
__global__ void prop_kernel(const u16* __restrict__ in,
                            u16* __restrict__ outu, int ldu, int cOff,
                            u16* __restrict__ outs,
                            const int* __restrict__ off, const int* __restrict__ srcs,
                            const float* __restrict__ norm, int nnodes) {
  const int node = blockIdx.x * 4 + (threadIdx.x >> 6);
  if (node >= nnodes) return;
  const int lane = threadIdx.x & 63;
  const int e0 = off[node], e1 = off[node + 1];
  float a0 = 0.f, a1 = 0.f;
  const u16* basec = in + (lane << 1);
  for (int base = e0; base < e1; base += 64) {
    int nE = e1 - base; if (nE > 64) nE = 64;
    int myE = srcs[base + ((lane < nE) ? lane : (nE - 1))];
    int i = 0;
    for (; i + 8 <= nE; i += 8) {
      int s0 = __builtin_amdgcn_readlane(myE, i + 0);
      int s1 = __builtin_amdgcn_readlane(myE, i + 1);
      int s2 = __builtin_amdgcn_readlane(myE, i + 2);
      int s3 = __builtin_amdgcn_readlane(myE, i + 3);
      int s4 = __builtin_amdgcn_readlane(myE, i + 4);
      int s5 = __builtin_amdgcn_readlane(myE, i + 5);
      int s6 = __builtin_amdgcn_readlane(myE, i + 6);
      int s7 = __builtin_amdgcn_readlane(myE, i + 7);
      u32 v0 = *(const u32*)(basec + ((size_t)s0 << 7));
      u32 v1 = *(const u32*)(basec + ((size_t)s1 << 7));
      u32 v2 = *(const u32*)(basec + ((size_t)s2 << 7));
      u32 v3 = *(const u32*)(basec + ((size_t)s3 << 7));
      u32 v4 = *(const u32*)(basec + ((size_t)s4 << 7));
      u32 v5 = *(const u32*)(basec + ((size_t)s5 << 7));
      u32 v6 = *(const u32*)(basec + ((size_t)s6 << 7));
      u32 v7 = *(const u32*)(basec + ((size_t)s7 << 7));
      a0 += bf2f((u16)v0); a1 += bf2f((u16)(v0 >> 16));
      a0 += bf2f((u16)v1); a1 += bf2f((u16)(v1 >> 16));
      a0 += bf2f((u16)v2); a1 += bf2f((u16)(v2 >> 16));
      a0 += bf2f((u16)v3); a1 += bf2f((u16)(v3 >> 16));
      a0 += bf2f((u16)v4); a1 += bf2f((u16)(v4 >> 16));
      a0 += bf2f((u16)v5); a1 += bf2f((u16)(v5 >> 16));
      a0 += bf2f((u16)v6); a1 += bf2f((u16)(v6 >> 16));
      a0 += bf2f((u16)v7); a1 += bf2f((u16)(v7 >> 16));
    }
    for (; i < nE; ++i) {
      int s = __builtin_amdgcn_readlane(myE, i);
      u32 v = *(const u32*)(basec + ((size_t)s << 7));
      a0 += bf2f((u16)v); a1 += bf2f((u16)(v >> 16));
    }
  }
  float nd = norm[node];
  *(u32*)(outu + (size_t)node * ldu + cOff + (lane << 1)) = pk2(a0 * nd, a1 * nd);
  if (outs) {
    float nd2 = nd * nd;
    *(u32*)(outs + ((size_t)node << 7) + (lane << 1)) = pk2(a0 * nd2, a1 * nd2);
  }
}

// ---------------- proj: sims(fp32) GEMM, A-upfront, dbuf single-barrier ----------
// BM=32, BN=128, K=512. Grid = 2*gseg: first gseg -> H0 (HCAT cols 0-127 + scaled
// HSa); second gseg -> SB fp32 (fc1 sims-partial). d/m by inner idx.
__global__ __launch_bounds__(256) void proj_kernel(
    const float* __restrict__ dsim, const float* __restrict__ msim,
    const u16* __restrict__ Wdfc, const u16* __restrict__ Wmfc,
    const u16* __restrict__ Wdfc1s, const u16* __restrict__ Wmfc1s,
    const float* __restrict__ dfcb, const float* __restrict__ mfcb,
    int gdseg, int gseg,
    u16* __restrict__ HCAT, u16* __restrict__ HSa, float* __restrict__ SB,
    const float* __restrict__ normp) {
  __shared__ u32 As[2][32 * 32];     // 8 KB
  __shared__ u32 Ws[2][128 * 32];    // 32 KB
  const int tid = threadIdx.x;
  int b = (int)blockIdx.x;
  const bool sbseg = b >= gseg;
  if (sbseg) b -= gseg;
  const bool mseg = b >= gdseg;
  const int brow = mseg ? D_NODES + (b - gdseg) * 32 : b * 32;
  const int bound = mseg ? N_NODES : D_NODES;
  const float* A = mseg ? msim : dsim;   // global-row indexed
  const u16* W = sbseg ? (mseg ? Wmfc1s : Wdfc1s) : (mseg ? Wmfc : Wdfc);
  const float* bias = mseg ? mfcb : dfcb;

  const int lane = tid & 63, wv = tid >> 6;
  const int fr = lane & 15, fg = lane >> 4;
  const int sr = tid >> 3, sk = tid & 7;
  const int swc = tid >> 1, sh = tid & 1;
  const int prow = (brow + sr < bound) ? (brow + sr) : (bound - 1);

  // ---- all A upfront: 8 chunks x 8 fp32 -> bf16 regs (one latency exposure)
  const float* ap = A + (size_t)prow * 512 + sk * 8;
  uint4 aq[8];
#pragma unroll
  for (int j = 0; j < 8; ++j) {
    float4 f0 = ((const float4*)(ap + j * 64))[0];
    float4 f1 = ((const float4*)(ap + j * 64))[1];
    aq[j] = make_uint4(pk2(f0.x, f0.y), pk2(f0.z, f0.w), pk2(f1.x, f1.y), pk2(f1.z, f1.w));
  }

  const u16* wrow = W + (size_t)swc * 512 + sh * 32;
  uint4 pw0, pw1, pw2, pw3;
  // prologue: W(0) -> regs -> buf0 (with A(0)); W(1) -> regs
  pw0 = *(const uint4*)(wrow);
  pw1 = *(const uint4*)(wrow + 8);
  pw2 = *(const uint4*)(wrow + 16);
  pw3 = *(const uint4*)(wrow + 24);
  *(uint4*)&As[0][sr * 32 + (sk ^ (sr & 7)) * 4] = aq[0];
  *(uint4*)&Ws[0][swc * 32 + ((sh * 4 + 0) ^ (swc & 7)) * 4] = pw0;
  *(uint4*)&Ws[0][swc * 32 + ((sh * 4 + 1) ^ (swc & 7)) * 4] = pw1;
  *(uint4*)&Ws[0][swc * 32 + ((sh * 4 + 2) ^ (swc & 7)) * 4] = pw2;
  *(uint4*)&Ws[0][swc * 32 + ((sh * 4 + 3) ^ (swc & 7)) * 4] = pw3;
  {
    const u16* wp = wrow + 64;
    pw0 = *(const uint4*)(wp);
    pw1 = *(const uint4*)(wp + 8);
    pw2 = *(const uint4*)(wp + 16);
    pw3 = *(const uint4*)(wp + 24);
  }
  __syncthreads();

  f32x4 acc[2][2];
#pragma unroll
  for (int m = 0; m < 2; ++m)
#pragma unroll
    for (int n = 0; n < 2; ++n) acc[m][n] = (f32x4){0.f, 0.f, 0.f, 0.f};

#pragma unroll
  for (int j = 0; j < 8; ++j) {
    int cb = j & 1, nb = cb ^ 1;
    if (j < 7) {  // store tile j+1 into the other buffer (its readers finished at bar j-1)
      *(uint4*)&As[nb][sr * 32 + (sk ^ (sr & 7)) * 4] = aq[j + 1];
      *(uint4*)&Ws[nb][swc * 32 + ((sh * 4 + 0) ^ (swc & 7)) * 4] = pw0;
      *(uint4*)&Ws[nb][swc * 32 + ((sh * 4 + 1) ^ (swc & 7)) * 4] = pw1;
      *(uint4*)&Ws[nb][swc * 32 + ((sh * 4 + 2) ^ (swc & 7)) * 4] = pw2;
      *(uint4*)&Ws[nb][swc * 32 + ((sh * 4 + 3) ^ (swc & 7)) * 4] = pw3;
    }
    if (j < 6) {  // W(j+2) -> regs
      const u16* wp = wrow + (j + 2) * 64;
      pw0 = *(const uint4*)(wp);
      pw1 = *(const uint4*)(wp + 8);
      pw2 = *(const uint4*)(wp + 16);
      pw3 = *(const uint4*)(wp + 24);
    }
    mfma_block(As[cb], Ws[cb], fr, fg, wv, acc);
    __syncthreads();
  }

  // ---- epilogue: D lane map col=lane&15, row=(lane>>4)*4+i  [m89]
#pragma unroll
  for (int m = 0; m < 2; ++m) {
#pragma unroll
    for (int n = 0; n < 2; ++n) {
      int ccol = wv * 32 + n * 16 + fr;
#pragma unroll
      for (int i = 0; i < 4; ++i) {
        int row = brow + m * 16 + fg * 4 + i;
        if (row < bound) {
          if (sbseg) {
            SB[((size_t)row << 7) + ccol] = acc[m][n][i];
          } else {
            float v = acc[m][n][i] + bias[ccol];
            HCAT[(size_t)row * 640 + ccol] = f2bf(v);
            HSa[((size_t)row << 7) + ccol] = f2bf(v * normp[row]);
          }
        }
      }
    }
  }
}

// ---------------- bf16 MFMA GEMM (BM=32, BN=128, BK=64; NB = LDS buffers) --------
// NB=2: single-barrier double-buffered (dense GEMMs). NB=1: original 2-barrier
// (p0: gather-bound, keep 20KB LDS occupancy).
template <int NB>
__global__ __launch_bounds__(256) void gemm128_kernel(
    const u16* __restrict__ A1, int lda1, int K1,
    const u16* __restrict__ A2, int lda2, int K2,
    const int* __restrict__ gsrc, const int* __restrict__ gdst,
    const u16* __restrict__ Wa, const u16* __restrict__ Wb,
    const float* __restrict__ biasa, const float* __restrict__ biasb,
    int splitB, int rowD, int boundA, int nrows,
    u16* __restrict__ Cu, int ldcu,
    const float* __restrict__ SBadd,
    const float* __restrict__ p1w, const float* __restrict__ p1b, float* __restrict__ outf,
    int act) {
  __shared__ u32 As[NB][32 * 32];
  __shared__ u32 Ws[NB][128 * 32];
  const int tid = threadIdx.x;
  const bool segb = (int)blockIdx.x >= splitB;
  const int brow = segb ? rowD + ((int)blockIdx.x - splitB) * 32 : (int)blockIdx.x * 32;
  const int bound = segb ? nrows : boundA;
  const u16* W = segb ? Wb : Wa;
  const float* bias = segb ? biasb : biasa;
  const int K = K1 + K2;
  const int nIt = K >> 6;
  const int lane = tid & 63;
  const int wv = tid >> 6;
  const int fr = lane & 15;
  const int fg = lane >> 4;

  f32x4 acc[2][2];
#pragma unroll
  for (int m = 0; m < 2; ++m)
#pragma unroll
    for (int n = 0; n < 2; ++n) acc[m][n] = (f32x4){0.f, 0.f, 0.f, 0.f};

  const int sr = tid >> 3, sk = tid & 7;     // A: row, granule (8 bf16)
  const int swc = tid >> 1, sh = tid & 1;    // W: row, 32-elem half
  const int prow = (brow + sr < bound) ? (brow + sr) : (bound - 1);
  const int rA = gsrc ? gsrc[prow] : prow;
  const int rB = gsrc ? gdst[prow] : prow;

  uint4 pa, pw0, pw1, pw2, pw3;

#define LOADT(kc_) {                                                     \
    int kcv = (kc_);                                                     \
    bool seg1 = kcv < K1;                                                \
    int kk = (seg1 ? kcv : kcv - K1) + sk * 8;                           \
    const u16* Av = seg1 ? A1 : A2;                                      \
    int ld = seg1 ? lda1 : lda2;                                         \
    int row = seg1 ? rA : rB;                                            \
    pa = *(const uint4*)(Av + (size_t)row * ld + kk);                    \
    const u16* wp = W + (size_t)swc * K + kcv + sh * 32;                 \
    pw0 = *(const uint4*)(wp);                                           \
    pw1 = *(const uint4*)(wp + 8);                                       \
    pw2 = *(const uint4*)(wp + 16);                                      \
    pw3 = *(const uint4*)(wp + 24); }

#define STORET(b_) {                                                     \
    *(uint4*)&As[b_][sr * 32 + (sk ^ (sr & 7)) * 4] = pa;                \
    *(uint4*)&Ws[b_][swc * 32 + ((sh * 4 + 0) ^ (swc & 7)) * 4] = pw0;   \
    *(uint4*)&Ws[b_][swc * 32 + ((sh * 4 + 1) ^ (swc & 7)) * 4] = pw1;   \
    *(uint4*)&Ws[b_][swc * 32 + ((sh * 4 + 2) ^ (swc & 7)) * 4] = pw2;   \
    *(uint4*)&Ws[b_][swc * 32 + ((sh * 4 + 3) ^ (swc & 7)) * 4] = pw3; }

  if (NB == 2) {
    LOADT(0);
    STORET(0);
    if (nIt > 1) LOADT(64);
    __syncthreads();
    for (int j = 0; j < nIt; ++j) {
      int cb = j & 1, nb = cb ^ 1;
      if (j + 1 < nIt) STORET(nb);
      if (j + 2 < nIt) LOADT((j + 2) << 6);
      mfma_block(As[cb], Ws[cb], fr, fg, wv, acc);
      __syncthreads();
    }
  } else {
    for (int kc = 0; kc < K; kc += 64) {
      LOADT(kc);
      __syncthreads();
      STORET(0);
      __syncthreads();
      mfma_block(As[0], Ws[0], fr, fg, wv, acc);
    }
  }
#undef LOADT
#undef STORET

  if (act == 3) {
    float part[2][4];
#pragma unroll
    for (int m = 0; m < 2; ++m)
#pragma unroll
      for (int i = 0; i < 4; ++i) part[m][i] = 0.f;
#pragma unroll
    for (int n = 0; n < 2; ++n) {
      int ccol = wv * 32 + n * 16 + fr;
      float b = bias[ccol];
      float pw = p1w[ccol];
#pragma unroll
      for (int m = 0; m < 2; ++m)
#pragma unroll
        for (int i = 0; i < 4; ++i) {
          float v = fmaxf(acc[m][n][i] + b, 0.f);
          part[m][i] += v * pw;
        }
    }
#pragma unroll
    for (int mask = 1; mask <= 8; mask <<= 1)
#pragma unroll
      for (int m = 0; m < 2; ++m)
#pragma unroll
        for (int i = 0; i < 4; ++i) part[m][i] += __shfl_xor(part[m][i], mask);
    __syncthreads();
    float* sred = (float*)&As[0][0];   // [4][32]
    if (fr == 0) {
#pragma unroll
      for (int m = 0; m < 2; ++m)
#pragma unroll
        for (int i = 0; i < 4; ++i) sred[wv * 32 + m * 16 + fg * 4 + i] = part[m][i];
    }
    __syncthreads();
    if (tid < 32) {
      int row = brow + tid;
      if (row < bound) {
        float s = sred[tid] + sred[32 + tid] + sred[64 + tid] + sred[96 + tid] + p1b[0];
        outf[row] = 1.f / (1.f + expf(-s));
      }
    }
    return;
  }

  // ---- epilogue: D lane map col=lane&15, row=(lane>>4)*4+i  [m89]
#pragma unroll
  for (int m = 0; m < 2; ++m) {
#pragma unroll
    for (int n = 0; n < 2; ++n) {
      int ccol = wv * 32 + n * 16 + fr;
      float b = bias ? bias[ccol] : 0.f;
#pragma unroll
      for (int i = 0; i < 4; ++i) {
        int row = brow + m * 16 + fg * 4 + i;
        if (row < bound) {
          float v = acc[m][n][i] + b;
          if (SBadd) v += SBadd[((size_t)row << 7) + ccol];
          if (act == 1) v = (v > 0.f) ? v : (expf(v) - 1.f);
          Cu[(size_t)row * ldcu + ccol] = f2bf(v);
        }
      }
    }
  }
}

// ---------------- host launcher ----------------
extern "C" void kernel_launch(void* const* d_in, const int* in_sizes, int n_in,
                              void* d_out, int out_size, void* d_ws, size_t ws_size,
                              hipStream_t stream) {
  const float* d_sim   = (const float*)d_in[0];
  const float* m_sim   = (const float*)d_in[1];
  const int*   e_src   = (const int*)d_in[2];
  const int*   e_dst   = (const int*)d_in[3];
  const int*   p_src   = (const int*)d_in[4];
  const int*   p_dst   = (const int*)d_in[5];
  const float* d_fc_w  = (const float*)d_in[6];
  const float* d_fc_b  = (const float*)d_in[7];
  const float* m_fc_w  = (const float*)d_in[8];
  const float* m_fc_b  = (const float*)d_in[9];
  const float* l0_w    = (const float*)d_in[10];
  const float* l1_w    = (const float*)d_in[11];
  const float* fc_w    = (const float*)d_in[12];
  const float* d_fc1_w = (const float*)d_in[13];
  const float* d_fc1_b = (const float*)d_in[14];
  const float* m_fc1_w = (const float*)d_in[15];
  const float* m_fc1_b = (const float*)d_in[16];
  const float* p0_w    = (const float*)d_in[17];
  const float* p0_b    = (const float*)d_in[18];
  const float* p1_w    = (const float*)d_in[19];
  const float* p1_b    = (const float*)d_in[20];
  float* out = (float*)d_out;

  const int N = N_NODES, D = D_NODES, M = M_NODES, E = E_EDGES, NP = PAIRS_N;

  // ---- workspace layout (u16 units)
  u16* ws16 = (u16*)d_ws;
  u16* HCAT = ws16;                         // [N,640]
  u16* HSa  = HCAT + (size_t)N * 640;       // [N,128]
  u16* HSb  = HSa + (size_t)N * 128;        // [N,128]
  u16* FE   = HSb + (size_t)N * 128;        // [N,128] feats
  u16* HB   = FE  + (size_t)N * 128;        // [N,128] h
  u16* wb_dfc   = HB + (size_t)N * 128;     // 65536
  u16* wb_mfc   = wb_dfc   + 65536;
  u16* wb_dfc1s = wb_mfc   + 65536;         // 65536
  u16* wb_mfc1s = wb_dfc1s + 65536;
  u16* wb_dfc1f = wb_mfc1s + 65536;         // 16384
  u16* wb_mfc1f = wb_dfc1f + 16384;
  u16* wb_p0    = wb_mfc1f + 16384;         // 32768
  u16* wb_G     = wb_p0    + 32768;         // 81920 ([128][640])
  u16* wend     = wb_G     + 81920;
  size_t off16 = (size_t)(wend - ws16);
  off16 = (off16 + 1) & ~(size_t)1;
  float* SB    = (float*)(ws16 + off16);    // [N,128] f32
  float* Tmp   = SB + (size_t)N * 128;      // 9*128*128 f32
  float* normp = Tmp + 9 * 16384;
  int* degs    = (int*)(normp + N);
  int* csr_off = degs + N;                  // N+1
  int* cursor  = csr_off + N + 1;           // N
  int* csr_src = cursor + N;                // E
  int* bsums   = csr_src + E;               // <=256

  const int nb = (N + 255) / 256;
  const int eb = (E + 255) / 256;

  // ---- weight prep + combine (independent of graph)
  wprep_kernel<<<320, 256, 0, stream>>>(d_fc_w, m_fc_w, d_fc1_w, m_fc1_w, p0_w,
                                        wb_dfc, wb_mfc, wb_dfc1s, wb_mfc1s,
                                        wb_dfc1f, wb_mfc1f, wb_p0);
  wcomb1_kernel<<<dim3(9, 128), 128, 0, stream>>>(l1_w, l0_w, Tmp);
  wcomb2_kernel<<<dim3(5, 128), 128, 0, stream>>>(fc_w, Tmp, wb_G);

  // ---- degrees, norm, CSR-by-dst
  zero_int_kernel<<<nb, 256, 0, stream>>>(degs, N);
  deg_count_kernel<<<eb, 256, 0, stream>>>(e_dst, degs, E);
  norm_reduce_kernel<<<nb, 256, 0, stream>>>(degs, normp, N, bsums);
  scan_small_kernel<<<1, 256, 0, stream>>>(bsums, nb);
  scan_final_kernel<<<nb, 256, 0, stream>>>(degs, bsums, csr_off, cursor, N, E);
  fill_csr_kernel<<<eb, 256, 0, stream>>>(e_src, e_dst, cursor, csr_src, E);

  const int GDseg = D / 32;                  // 625
  const int GMseg = (M + 31) / 32;           // 938
  const int GSEG = GDseg + GMseg;            // 1563
  const int GN = (N + 31) / 32;              // 1563
  const int GP = (NP + 31) / 32;             // 3125
  const int GPROP = (N + 3) / 4;             // 12500

  // ---- proj (grid 2x: H0 + SB partial, one sims read window)
  proj_kernel<<<2 * GSEG, 256, 0, stream>>>(
      d_sim, m_sim, wb_dfc, wb_mfc, wb_dfc1s, wb_mfc1s, d_fc_b, m_fc_b,
      GDseg, GSEG, HCAT, HSa, SB, normp);

  // ---- 4 sequential 128-wide props: H1..H4 -> HCAT col-blocks, scaled ping-pong
  prop_kernel<<<GPROP, 256, 0, stream>>>(HSa, HCAT, 640, 128, HSb, csr_off, csr_src, normp, N);
  prop_kernel<<<GPROP, 256, 0, stream>>>(HSb, HCAT, 640, 256, HSa, csr_off, csr_src, normp, N);
  prop_kernel<<<GPROP, 256, 0, stream>>>(HSa, HCAT, 640, 384, HSb, csr_off, csr_src, normp, N);
  prop_kernel<<<GPROP, 256, 0, stream>>>(HSb, HCAT, 640, 512, nullptr, csr_off, csr_src, normp, N);

  // ---- collapsed mixhop+fc: feats = HCAT [N,640] @ G^T -> FE   (dbuf)
  gemm128_kernel<2><<<GN, 256, 0, stream>>>(
      HCAT, 640, 640, HCAT, 640, 0, nullptr, nullptr,
      wb_G, wb_G, nullptr, nullptr, GN, 0, N, N,
      FE, 128, nullptr, nullptr, nullptr, nullptr, 0);

  // ---- fc1-lite (+SB +bias, ELU): h -> HB   (dbuf)
  gemm128_kernel<2><<<GSEG, 256, 0, stream>>>(
      FE, 128, 128, FE, 128, 0, nullptr, nullptr,
      wb_dfc1f, wb_mfc1f, d_fc1_b, m_fc1_b, GDseg, D, D, N,
      HB, 128, SB, nullptr, nullptr, nullptr, 1);

  // ---- predictor p0 (gathered concat) + ReLU + dot(p1) + sigmoid -> out (1-buf)
  gemm128_kernel<1><<<GP, 256, 0, stream>>>(
      HB, 128, 128, HB, 128, 128, p_src, p_dst,
      wb_p0, wb_p0, p0_b, p0_b, GP, 0, NP, NP,
      nullptr, 128, nullptr, p1_w, p1_b, out, 3);

  (void)in_sizes; (void)n_in; (void)out_size; (void)ws_size;
}

// Round 12
// 384.193 us; speedup vs baseline: 1.1017x; 1.0759x over previous
//
#include <hip/hip_runtime.h>
#include <cstddef>
#include <cstdint>

#define N_NODES 50000
#define D_NODES 20000
#define M_NODES 30000
#define E_EDGES 800000
#define PAIRS_N 100000

typedef unsigned short u16;
typedef unsigned int u32;
typedef short bf16x8 __attribute__((ext_vector_type(8)));
typedef float f32x4 __attribute__((ext_vector_type(4)));

__device__ __forceinline__ float bf2f(u16 u) {
  u32 v = ((u32)u) << 16;
  return __builtin_bit_cast(float, v);
}
__device__ __forceinline__ u16 f2bf(float f) {
  u32 u = __builtin_bit_cast(u32, f);
  u32 r = (u + 0x7fffu + ((u >> 16) & 1u)) >> 16;  // RNE
  return (u16)r;
}
__device__ __forceinline__ u32 pk2(float x, float y) {
  return (u32)f2bf(x) | ((u32)f2bf(y) << 16);
}

// ---------------- weight conversion (5 mats -> bf16, one launch) ----------------
__global__ void wconv_kernel(const float* s0, const float* s1, const float* s2,
                             const float* s3, const float* s4,
                             u16* d0, u16* d1, u16* d2, u16* d3, u16* d4) {
  int i = blockIdx.x * 256 + threadIdx.x;  // quad index
  const float* s; u16* d; int l;
  if      (i < 16384) { s = s0; d = d0; l = i; }
  else if (i < 32768) { s = s1; d = d1; l = i - 16384; }
  else if (i < 53248) { s = s2; d = d2; l = i - 32768; }
  else if (i < 73728) { s = s3; d = d3; l = i - 53248; }
  else if (i < 81920) { s = s4; d = d4; l = i - 73728; }
  else return;
  float4 v = *(const float4*)(s + (size_t)l * 4);
  ushort4 o;
  o.x = f2bf(v.x); o.y = f2bf(v.y); o.z = f2bf(v.z); o.w = f2bf(v.w);
  *(ushort4*)(d + (size_t)l * 4) = o;
}

// ---------------- weight combine: G_k = sum_{p+j=k} fc_p * W'_pj * W_j ----------
__global__ void wcomb1_kernel(const float* __restrict__ l1w, const float* __restrict__ l0w,
                              float* __restrict__ Tmp) {
  int pj = blockIdx.x;          // 0..8
  int p = pj / 3, j = pj % 3;
  int o = blockIdx.y;           // 0..127
  int i = threadIdx.x;          // 0..127
  const float* wp = l1w + (size_t)p * 49152 + (size_t)o * 384 + 128 * j;
  const float* wj = l0w + (size_t)j * 16384 + i;
  float acc = 0.f;
#pragma unroll 4
  for (int t = 0; t < 128; ++t) acc += wp[t] * wj[(size_t)t * 128];
  Tmp[(size_t)pj * 16384 + (size_t)o * 128 + i] = acc;
}
__global__ void wcomb2_kernel(const float* __restrict__ fcw, const float* __restrict__ Tmp,
                              u16* __restrict__ G) {
  int k = blockIdx.x;           // 0..4
  int of = blockIdx.y;          // 0..127
  int i = threadIdx.x;          // 0..127
  float acc = 0.f;
  int plo = (k > 2) ? (k - 2) : 0;
  int phi = (k < 2) ? k : 2;
  for (int p = plo; p <= phi; ++p) {
    int j = k - p;
    const float* fp = fcw + (size_t)of * 384 + 128 * p;
    const float* tp = Tmp + (size_t)(p * 3 + j) * 16384 + i;
#pragma unroll 4
    for (int t = 0; t < 128; ++t) acc += fp[t] * tp[(size_t)t * 128];
  }
  G[(size_t)of * 640 + 128 * k + i] = f2bf(acc);
}

// ---------------- CSR build ----------------
__global__ void zero_int_kernel(int* p, int n) {
  int i = blockIdx.x * 256 + threadIdx.x;
  if (i < n) p[i] = 0;
}
__global__ void deg_count_kernel(const int* __restrict__ dst, int* __restrict__ degs, int e) {
  int i = blockIdx.x * 256 + threadIdx.x;
  if (i < e) atomicAdd(&degs[dst[i]], 1);
}
__global__ void norm_reduce_kernel(const int* __restrict__ degs, float* __restrict__ norm,
                                   int n, int* __restrict__ bsums) {
  __shared__ int s[256];
  int t = threadIdx.x;
  int i = blockIdx.x * 256 + t;
  int d = (i < n) ? degs[i] : 0;
  if (i < n) norm[i] = rsqrtf(fmaxf((float)d, 1.0f));
  s[t] = d;
  __syncthreads();
  for (int st = 128; st > 0; st >>= 1) {
    if (t < st) s[t] += s[t + st];
    __syncthreads();
  }
  if (t == 0) bsums[blockIdx.x] = s[0];
}
__global__ void scan_small_kernel(int* b, int nb) {
  __shared__ int s[256];
  int t = threadIdx.x;
  int orig = (t < nb) ? b[t] : 0;
  s[t] = orig;
  __syncthreads();
  for (int st = 1; st < 256; st <<= 1) {
    int v = (t >= st) ? s[t - st] : 0;
    __syncthreads();
    s[t] += v;
    __syncthreads();
  }
  if (t < nb) b[t] = s[t] - orig;
}
__global__ void scan_final_kernel(const int* __restrict__ degs, const int* __restrict__ boff,
                                  int* __restrict__ out, int* __restrict__ cursor,
                                  int n, int total) {
  __shared__ int s[256];
  int t = threadIdx.x;
  int i = blockIdx.x * 256 + t;
  int orig = (i < n) ? degs[i] : 0;
  s[t] = orig;
  __syncthreads();
  for (int st = 1; st < 256; st <<= 1) {
    int v = (t >= st) ? s[t - st] : 0;
    __syncthreads();
    s[t] += v;
    __syncthreads();
  }
  if (i < n) {
    int v = boff[blockIdx.x] + s[t] - orig;
    out[i] = v;
    cursor[i] = v;
  }
  if (i == 0) out[n] = total;
}
__global__ void fill_csr_kernel(const int* __restrict__ esrc, const int* __restrict__ edst,
                                int* __restrict__ cursor, int* __restrict__ csr_src, int e) {
  int i = blockIdx.x * 256 + threadIdx.x;
  if (i < e) {
    int p = atomicAdd(&cursor[edst[i]], 1);
    csr_src[p] = esrc[i];
  }
}

// ---------------- wave-per-node 128-wide propagation on pre-scaled input --------
__global__ void prop_kernel(const u16* __restrict__ in,
                            u16* __restrict__ outu, int ldu, int cOff,
                            u16* __restrict__ outs,
                            const int* __restrict__ off, const int* __restrict__ srcs,
                            const float* __restrict__ norm, int nnodes) {
  const int node = blockIdx.x * 4 + (threadIdx.x >> 6);
  if (node >= nnodes) return;
  const int lane = threadIdx.x & 63;
  const int e0 = off[node], e1 = off[node + 1];
  float a0 = 0.f, a1 = 0.f;
  const u16* basec = in + (lane << 1);
  for (int base = e0; base < e1; base += 64) {
    int nE = e1 - base; if (nE > 64) nE = 64;
    int myE = srcs[base + ((lane < nE) ? lane : (nE - 1))];
    int i = 0;
    for (; i + 8 <= nE; i += 8) {
      int s0 = __builtin_amdgcn_readlane(myE, i + 0);
      int s1 = __builtin_amdgcn_readlane(myE, i + 1);
      int s2 = __builtin_amdgcn_readlane(myE, i + 2);
      int s3 = __builtin_amdgcn_readlane(myE, i + 3);
      int s4 = __builtin_amdgcn_readlane(myE, i + 4);
      int s5 = __builtin_amdgcn_readlane(myE, i + 5);
      int s6 = __builtin_amdgcn_readlane(myE, i + 6);
      int s7 = __builtin_amdgcn_readlane(myE, i + 7);
      u32 v0 = *(const u32*)(basec + ((size_t)s0 << 7));
      u32 v1 = *(const u32*)(basec + ((size_t)s1 << 7));
      u32 v2 = *(const u32*)(basec + ((size_t)s2 << 7));
      u32 v3 = *(const u32*)(basec + ((size_t)s3 << 7));
      u32 v4 = *(const u32*)(basec + ((size_t)s4 << 7));
      u32 v5 = *(const u32*)(basec + ((size_t)s5 << 7));
      u32 v6 = *(const u32*)(basec + ((size_t)s6 << 7));
      u32 v7 = *(const u32*)(basec + ((size_t)s7 << 7));
      a0 += bf2f((u16)v0); a1 += bf2f((u16)(v0 >> 16));
      a0 += bf2f((u16)v1); a1 += bf2f((u16)(v1 >> 16));
      a0 += bf2f((u16)v2); a1 += bf2f((u16)(v2 >> 16));
      a0 += bf2f((u16)v3); a1 += bf2f((u16)(v3 >> 16));
      a0 += bf2f((u16)v4); a1 += bf2f((u16)(v4 >> 16));
      a0 += bf2f((u16)v5); a1 += bf2f((u16)(v5 >> 16));
      a0 += bf2f((u16)v6); a1 += bf2f((u16)(v6 >> 16));
      a0 += bf2f((u16)v7); a1 += bf2f((u16)(v7 >> 16));
    }
    for (; i < nE; ++i) {
      int s = __builtin_amdgcn_readlane(myE, i);
      u32 v = *(const u32*)(basec + ((size_t)s << 7));
      a0 += bf2f((u16)v); a1 += bf2f((u16)(v >> 16));
    }
  }
  float nd = norm[node];
  *(u32*)(outu + (size_t)node * ldu + cOff + (lane << 1)) = pk2(a0 * nd, a1 * nd);
  if (outs) {
    float nd2 = nd * nd;
    *(u32*)(outs + ((size_t)node << 7) + (lane << 1)) = pk2(a0 * nd2, a1 * nd2);
  }
}

// ---------------- bf16 MFMA GEMM (BM=32, BK=64, XOR-swizzled LDS) ----------------
// Segmented (blocks >= splitB use b-pointers, rows from rowD). fp32 A converted in
// staging. Gather via gsrc/gdst. act: 0 none, 1 ELU, 2 ReLU, 3 fused p0+score.
__global__ __launch_bounds__(256) void mfma_gemm_kernel(
    const void* __restrict__ A1a, const void* __restrict__ A1b, int lda1, int K1, int a1f32,
    const void* __restrict__ A2a, const void* __restrict__ A2b, int lda2, int K2, int a2f32,
    const int* __restrict__ gsrc, const int* __restrict__ gdst,
    const u16* __restrict__ Wa, const u16* __restrict__ Wb,
    const float* __restrict__ biasa, const float* __restrict__ biasb,
    int splitB, int rowD, int boundA, int nrows,
    u16* __restrict__ Cu, int ldcu, int colOff,
    u16* __restrict__ Cs, const float* __restrict__ normp,
    const float* __restrict__ p1w, const float* __restrict__ p1b, float* __restrict__ outf,
    int act) {
  __shared__ u32 As[32 * 32];    // 4 KB
  __shared__ u32 Ws[128 * 32];   // 16 KB
  const int tid = threadIdx.x;
  const bool segb = (int)blockIdx.x >= splitB;
  const int brow = segb ? rowD + ((int)blockIdx.x - splitB) * 32 : (int)blockIdx.x * 32;
  const int bound = segb ? nrows : boundA;
  const void* A1 = segb ? A1b : A1a;
  const void* A2 = segb ? A2b : A2a;
  const u16* W = segb ? Wb : Wa;
  const float* bias = segb ? biasb : biasa;
  const int K = K1 + K2;
  const int lane = tid & 63;
  const int wv = tid >> 6;
  const int fr = lane & 15;
  const int fg = lane >> 4;

  f32x4 acc[2][2];
#pragma unroll
  for (int m = 0; m < 2; ++m)
#pragma unroll
    for (int n = 0; n < 2; ++n) acc[m][n] = (f32x4){0.f, 0.f, 0.f, 0.f};

  const int sr = tid >> 3, sk = tid & 7;     // A: row, granule (8 bf16)
  const int swc = tid >> 1, sh = tid & 1;    // W: row, 32-elem half
  const int prow = (brow + sr < bound) ? (brow + sr) : (bound - 1);

  for (int kc = 0; kc < K; kc += 64) {
    // ---- A: 8 k-elems per thread
    uint4 qa;
    {
      bool seg1 = kc < K1;
      int kk = (seg1 ? kc : kc - K1) + sk * 8;
      const void* Av = seg1 ? A1 : A2;
      int ld = seg1 ? lda1 : lda2;
      int isf = seg1 ? a1f32 : a2f32;
      int row = gsrc ? (seg1 ? gsrc[prow] : gdst[prow]) : prow;
      if (isf) {
        const float* p = (const float*)Av + (size_t)row * ld + kk;
        float4 f0 = ((const float4*)p)[0];
        float4 f1 = ((const float4*)p)[1];
        qa = make_uint4(pk2(f0.x, f0.y), pk2(f0.z, f0.w), pk2(f1.x, f1.y), pk2(f1.z, f1.w));
      } else {
        qa = *(const uint4*)((const u16*)Av + (size_t)row * ld + kk);
      }
    }
    // ---- W: 32 k-elems per thread
    const u16* wp = W + (size_t)swc * K + kc + sh * 32;
    uint4 qw0 = *(const uint4*)(wp);
    uint4 qw1 = *(const uint4*)(wp + 8);
    uint4 qw2 = *(const uint4*)(wp + 16);
    uint4 qw3 = *(const uint4*)(wp + 24);

    __syncthreads();
    *(uint4*)&As[sr * 32 + (sk ^ (sr & 7)) * 4] = qa;
    *(uint4*)&Ws[swc * 32 + ((sh * 4 + 0) ^ (swc & 7)) * 4] = qw0;
    *(uint4*)&Ws[swc * 32 + ((sh * 4 + 1) ^ (swc & 7)) * 4] = qw1;
    *(uint4*)&Ws[swc * 32 + ((sh * 4 + 2) ^ (swc & 7)) * 4] = qw2;
    *(uint4*)&Ws[swc * 32 + ((sh * 4 + 3) ^ (swc & 7)) * 4] = qw3;
    __syncthreads();

#pragma unroll
    for (int kk2 = 0; kk2 < 2; ++kk2) {
      int gix = kk2 * 4 + fg;
      int r0 = fr, r1 = 16 + fr;
      bf16x8 aF0 = *(const bf16x8*)&As[r0 * 32 + (gix ^ (r0 & 7)) * 4];
      bf16x8 aF1 = *(const bf16x8*)&As[r1 * 32 + (gix ^ (r1 & 7)) * 4];
#pragma unroll
      for (int n = 0; n < 2; ++n) {
        int cr = wv * 32 + n * 16 + fr;
        bf16x8 bF = *(const bf16x8*)&Ws[cr * 32 + (gix ^ (cr & 7)) * 4];
        acc[0][n] = __builtin_amdgcn_mfma_f32_16x16x32_bf16(aF0, bF, acc[0][n], 0, 0, 0);
        acc[1][n] = __builtin_amdgcn_mfma_f32_16x16x32_bf16(aF1, bF, acc[1][n], 0, 0, 0);
      }
    }
  }

  if (act == 3) {
    // fused p0 bias+ReLU, dot with p1w, sigmoid -> outf[row]
    float part[2][4];
#pragma unroll
    for (int m = 0; m < 2; ++m)
#pragma unroll
      for (int i = 0; i < 4; ++i) part[m][i] = 0.f;
#pragma unroll
    for (int n = 0; n < 2; ++n) {
      int ccol = wv * 32 + n * 16 + fr;
      float b = bias[ccol];
      float pw = p1w[ccol];
#pragma unroll
      for (int m = 0; m < 2; ++m)
#pragma unroll
        for (int i = 0; i < 4; ++i) {
          float v = acc[m][n][i] + b;
          v = fmaxf(v, 0.f);
          part[m][i] += v * pw;
        }
    }
#pragma unroll
    for (int mask = 1; mask <= 8; mask <<= 1)
#pragma unroll
      for (int m = 0; m < 2; ++m)
#pragma unroll
        for (int i = 0; i < 4; ++i) part[m][i] += __shfl_xor(part[m][i], mask);
    __syncthreads();
    float* sred = (float*)As;        // [4][32]
    if (fr == 0) {
#pragma unroll
      for (int m = 0; m < 2; ++m)
#pragma unroll
        for (int i = 0; i < 4; ++i) sred[wv * 32 + m * 16 + fg * 4 + i] = part[m][i];
    }
    __syncthreads();
    if (tid < 32) {
      int row = brow + tid;
      if (row < bound) {
        float s = sred[tid] + sred[32 + tid] + sred[64 + tid] + sred[96 + tid] + p1b[0];
        outf[row] = 1.f / (1.f + expf(-s));
      }
    }
    return;
  }

  // ---- epilogue: D lane map col=lane&15, row=(lane>>4)*4+i  [m89]
#pragma unroll
  for (int m = 0; m < 2; ++m) {
#pragma unroll
    for (int n = 0; n < 2; ++n) {
      int ccol = wv * 32 + n * 16 + fr;
      float b = bias ? bias[ccol] : 0.f;
#pragma unroll
      for (int i = 0; i < 4; ++i) {
        int row = brow + m * 16 + fg * 4 + i;
        if (row < bound) {
          float v = acc[m][n][i] + b;
          if (act == 1) v = (v > 0.f) ? v : (expf(v) - 1.f);
          else if (act == 2) v = fmaxf(v, 0.f);
          Cu[(size_t)row * ldcu + colOff + ccol] = f2bf(v);
          if (Cs) Cs[((size_t)row << 7) + ccol] = f2bf(v * normp[row]);
        }
      }
    }
  }
}

// ---------------- host launcher ----------------
extern "C" void kernel_launch(void* const* d_in, const int* in_sizes, int n_in,
                              void* d_out, int out_size, void* d_ws, size_t ws_size,
                              hipStream_t stream) {
  const float* d_sim   = (const float*)d_in[0];
  const float* m_sim   = (const float*)d_in[1];
  const int*   e_src   = (const int*)d_in[2];
  const int*   e_dst   = (const int*)d_in[3];
  const int*   p_src   = (const int*)d_in[4];
  const int*   p_dst   = (const int*)d_in[5];
  const float* d_fc_w  = (const float*)d_in[6];
  const float* d_fc_b  = (const float*)d_in[7];
  const float* m_fc_w  = (const float*)d_in[8];
  const float* m_fc_b  = (const float*)d_in[9];
  const float* l0_w    = (const float*)d_in[10];
  const float* l1_w    = (const float*)d_in[11];
  const float* fc_w    = (const float*)d_in[12];
  const float* d_fc1_w = (const float*)d_in[13];
  const float* d_fc1_b = (const float*)d_in[14];
  const float* m_fc1_w = (const float*)d_in[15];
  const float* m_fc1_b = (const float*)d_in[16];
  const float* p0_w    = (const float*)d_in[17];
  const float* p0_b    = (const float*)d_in[18];
  const float* p1_w    = (const float*)d_in[19];
  const float* p1_b    = (const float*)d_in[20];
  float* out = (float*)d_out;

  const int N = N_NODES, D = D_NODES, M = M_NODES, E = E_EDGES, NP = PAIRS_N;

  // ---- workspace layout (u16 units)
  u16* ws16 = (u16*)d_ws;
  u16* HCAT = ws16;                         // [N,640]
  u16* HSa  = HCAT + (size_t)N * 640;       // [N,128]
  u16* HSb  = HSa + (size_t)N * 128;        // [N,128]
  u16* FE   = HSb + (size_t)N * 128;        // [N,128] feats
  u16* HB   = FE  + (size_t)N * 128;        // [N,128] h
  u16* wb_dfc  = HB + (size_t)N * 128;      // 65536
  u16* wb_mfc  = wb_dfc  + 65536;
  u16* wb_dfc1 = wb_mfc  + 65536;           // 81920
  u16* wb_mfc1 = wb_dfc1 + 81920;
  u16* wb_p0   = wb_mfc1 + 81920;           // 32768
  u16* wb_G    = wb_p0   + 32768;           // 81920 ([128][640])
  u16* wend    = wb_G    + 81920;
  size_t off16 = (size_t)(wend - ws16);
  off16 = (off16 + 1) & ~(size_t)1;
  float* Tmp   = (float*)(ws16 + off16);    // 9*128*128 f32
  float* normp = Tmp + 9 * 16384;
  int* degs    = (int*)(normp + N);
  int* csr_off = degs + N;                  // N+1
  int* cursor  = csr_off + N + 1;           // N
  int* csr_src = cursor + N;                // E
  int* bsums   = csr_src + E;               // <=256

  const int nb = (N + 255) / 256;
  const int eb = (E + 255) / 256;

  // ---- weights -> bf16 ; weight combine (independent of graph/CSR)
  wconv_kernel<<<320, 256, 0, stream>>>(d_fc_w, m_fc_w, d_fc1_w, m_fc1_w, p0_w,
                                        wb_dfc, wb_mfc, wb_dfc1, wb_mfc1, wb_p0);
  wcomb1_kernel<<<dim3(9, 128), 128, 0, stream>>>(l1_w, l0_w, Tmp);
  wcomb2_kernel<<<dim3(5, 128), 128, 0, stream>>>(fc_w, Tmp, wb_G);

  // ---- degrees, norm, CSR-by-dst
  zero_int_kernel<<<nb, 256, 0, stream>>>(degs, N);
  deg_count_kernel<<<eb, 256, 0, stream>>>(e_dst, degs, E);
  norm_reduce_kernel<<<nb, 256, 0, stream>>>(degs, normp, N, bsums);
  scan_small_kernel<<<1, 256, 0, stream>>>(bsums, nb);
  scan_final_kernel<<<nb, 256, 0, stream>>>(degs, bsums, csr_off, cursor, N, E);
  fill_csr_kernel<<<eb, 256, 0, stream>>>(e_src, e_dst, cursor, csr_src, E);

  const int GDseg = D / 32;                  // 625
  const int GMseg = (M + 31) / 32;           // 938
  const int GSEG = GDseg + GMseg;
  const int GN = (N + 31) / 32;              // 1563
  const int GP = (NP + 31) / 32;             // 3125
  const int GPROP = (N + 3) / 4;             // 12500

  // ---- proj (segmented d/m, fp32 A): H0 -> HCAT[:,0:128], scaled H0 -> HSa
  mfma_gemm_kernel<<<GSEG, 256, 0, stream>>>(
      d_sim, m_sim, 512, 512, 1, nullptr, nullptr, 0, 0, 0, nullptr, nullptr,
      wb_dfc, wb_mfc, d_fc_b, m_fc_b, GDseg, D, D, N,
      HCAT, 640, 0, HSa, normp, nullptr, nullptr, nullptr, 0);

  // ---- 4 sequential 128-wide props: H1..H4 -> HCAT col-blocks, scaled ping-pong
  prop_kernel<<<GPROP, 256, 0, stream>>>(HSa, HCAT, 640, 128, HSb, csr_off, csr_src, normp, N);
  prop_kernel<<<GPROP, 256, 0, stream>>>(HSb, HCAT, 640, 256, HSa, csr_off, csr_src, normp, N);
  prop_kernel<<<GPROP, 256, 0, stream>>>(HSa, HCAT, 640, 384, HSb, csr_off, csr_src, normp, N);
  prop_kernel<<<GPROP, 256, 0, stream>>>(HSb, HCAT, 640, 512, nullptr, csr_off, csr_src, normp, N);

  // ---- collapsed mixhop+fc: feats = HCAT [N,640] @ G^T -> FE
  mfma_gemm_kernel<<<GN, 256, 0, stream>>>(
      HCAT, HCAT, 640, 640, 0, nullptr, nullptr, 0, 0, 0, nullptr, nullptr,
      wb_G, wb_G, nullptr, nullptr, GN, 0, N, N,
      FE, 128, 0, nullptr, normp, nullptr, nullptr, nullptr, 0);

  // ---- fc1 (+ELU, segmented d/m, A2 = fp32 sims): h -> HB
  mfma_gemm_kernel<<<GSEG, 256, 0, stream>>>(
      FE, FE, 128, 128, 0, d_sim, m_sim, 512, 512, 1, nullptr, nullptr,
      wb_dfc1, wb_mfc1, d_fc1_b, m_fc1_b, GDseg, D, D, N,
      HB, 128, 0, nullptr, normp, nullptr, nullptr, nullptr, 1);

  // ---- predictor p0 (gathered concat) + ReLU + dot(p1) + sigmoid -> out
  mfma_gemm_kernel<<<GP, 256, 0, stream>>>(
      HB, HB, 128, 128, 0, HB, HB, 128, 128, 0, p_src, p_dst,
      wb_p0, wb_p0, p0_b, p0_b, GP, 0, NP, NP,
      nullptr, 128, 0, nullptr, normp, p1_w, p1_b, out, 3);

  (void)in_sizes; (void)n_in; (void)out_size; (void)ws_size;
}